// Round 1
// baseline (1117.795 us; speedup 1.0000x reference)
//
#include <hip/hip_runtime.h>

#define NV 100000
#define NE 1600000
#define NB 2
#define FIN 32
#define NK 4
#define FOUT 32

// dst[i] = alpha * src[i]   (alpha=0 -> zero init; src may alias dst)
__global__ void scale_init_kernel(float* __restrict__ dst, const float* __restrict__ src,
                                  float alpha, int n) {
    int i = blockIdx.x * blockDim.x + threadIdx.x;
    if (i < n) dst[i] = alpha * src[i];
}

// y[b, rows[e], f] += scale * vals[e] * x[b, cols[e], f]
__global__ void spmm_scatter_kernel(float* __restrict__ y, const float* __restrict__ x,
                                    const int* __restrict__ rows, const int* __restrict__ cols,
                                    const float* __restrict__ vals, float scale) {
    long tid = (long)blockIdx.x * blockDim.x + threadIdx.x;
    int e = (int)(tid >> 5);
    int f = (int)(tid & 31);
    if (e >= NE) return;
    int r = rows[e];
    int c = cols[e];
    float v = scale * vals[e];
#pragma unroll
    for (int b = 0; b < NB; ++b) {
        float g = x[(long)b * NV * FIN + (long)c * FIN + f];
        atomicAdd(&y[(long)b * NV * FIN + (long)r * FIN + f], v * g);
    }
}

// out[r, o] (+)= sum_f x[r, f] * W[f, k, o]  (+ bias[o] when first)
// block = 256 threads = 8 rows x 32 outs; grid = B*V/8 = 25000
__global__ void term_gemm_kernel(float* __restrict__ out, const float* __restrict__ x,
                                 const float* __restrict__ weight, const float* __restrict__ bias,
                                 int k, int first) {
    __shared__ float Wl[FIN][FOUT];
    __shared__ float Xl[8][FIN];
    int tid = threadIdx.x;
    for (int i = tid; i < FIN * FOUT; i += 256) {
        int f = i >> 5, o = i & 31;
        Wl[f][o] = weight[f * (NK * FOUT) + k * FOUT + o];
    }
    long rbase = (long)blockIdx.x * 8;
    for (int i = tid; i < 8 * FIN; i += 256) {
        int rv = i >> 5, f = i & 31;
        Xl[rv][f] = x[(rbase + rv) * FIN + f];
    }
    __syncthreads();
    int rv = tid >> 5, o = tid & 31;
    float acc = 0.f;
#pragma unroll
    for (int f = 0; f < FIN; ++f) acc += Xl[rv][f] * Wl[f][o];
    long r = rbase + rv;
    if (first) out[r * FOUT + o] = acc + bias[o];
    else       out[r * FOUT + o] += acc;
}

extern "C" void kernel_launch(void* const* d_in, const int* in_sizes, int n_in,
                              void* d_out, int out_size, void* d_ws, size_t ws_size,
                              hipStream_t stream) {
    const float* inputs = (const float*)d_in[0];   // [B, V, FIN]
    const int*   rows   = (const int*)d_in[1];     // [E]
    const int*   cols   = (const int*)d_in[2];     // [E]
    const float* vals   = (const float*)d_in[3];   // [E]
    const float* weight = (const float*)d_in[4];   // [FIN, K, FOUT]
    const float* bias   = (const float*)d_in[5];   // [FOUT]
    float* out  = (float*)d_out;                   // [B, V, FOUT]
    float* bufA = (float*)d_ws;                    // [B, V, FIN]
    float* bufB = bufA + (long)NB * NV * FIN;      // [B, V, FIN]

    const int n = NB * NV * FIN;                   // 6.4M
    const int gN = (n + 255) / 256;
    const int gE = (NE * 32 + 255) / 256;          // 200000 blocks
    const int gG = (NB * NV) / 8;                  // 25000 blocks

    // term 0: out = bias + x0 @ W0
    term_gemm_kernel<<<gG, 256, 0, stream>>>(out, inputs, weight, bias, 0, 1);

    // x1 = L x0  (bufA)
    scale_init_kernel<<<gN, 256, 0, stream>>>(bufA, inputs, 0.f, n);
    spmm_scatter_kernel<<<gE, 256, 0, stream>>>(bufA, inputs, rows, cols, vals, 1.f);
    term_gemm_kernel<<<gG, 256, 0, stream>>>(out, bufA, weight, bias, 1, 0);

    // x2 = 2 L x1 - x0  (bufB)
    scale_init_kernel<<<gN, 256, 0, stream>>>(bufB, inputs, -1.f, n);
    spmm_scatter_kernel<<<gE, 256, 0, stream>>>(bufB, bufA, rows, cols, vals, 2.f);
    term_gemm_kernel<<<gG, 256, 0, stream>>>(out, bufB, weight, bias, 2, 0);

    // x3 = 2 L x2 - x1  (bufA, in place negate then scatter)
    scale_init_kernel<<<gN, 256, 0, stream>>>(bufA, bufA, -1.f, n);
    spmm_scatter_kernel<<<gE, 256, 0, stream>>>(bufA, bufB, rows, cols, vals, 2.f);
    term_gemm_kernel<<<gG, 256, 0, stream>>>(out, bufA, weight, bias, 3, 0);
}

// Round 2
// 606.132 us; speedup vs baseline: 1.8441x; 1.8441x over previous
//
#include <hip/hip_runtime.h>

#define NV 100000
#define NE 1600000
#define NB 2
#define FIN 32
#define NK 4
#define FOUT 32
#define SCAN_B 256

// ---------------- fallback (round-0) kernels ----------------

__global__ void scale_init_kernel(float* __restrict__ dst, const float* __restrict__ src,
                                  float alpha, int n) {
    int i = blockIdx.x * blockDim.x + threadIdx.x;
    if (i < n) dst[i] = alpha * src[i];
}

__global__ void spmm_scatter_kernel(float* __restrict__ y, const float* __restrict__ x,
                                    const int* __restrict__ rows, const int* __restrict__ cols,
                                    const float* __restrict__ vals, float scale) {
    long tid = (long)blockIdx.x * blockDim.x + threadIdx.x;
    int e = (int)(tid >> 5);
    int f = (int)(tid & 31);
    if (e >= NE) return;
    int r = rows[e];
    int c = cols[e];
    float v = scale * vals[e];
#pragma unroll
    for (int b = 0; b < NB; ++b) {
        float g = x[(long)b * NV * FIN + (long)c * FIN + f];
        atomicAdd(&y[(long)b * NV * FIN + (long)r * FIN + f], v * g);
    }
}

// ---------------- CSR build ----------------

__global__ void zero_counts_kernel(int* __restrict__ counts) {
    int v = blockIdx.x * blockDim.x + threadIdx.x;
    if (v < NV) counts[v] = 0;
}

__global__ void hist_kernel(const int* __restrict__ rows, int* __restrict__ counts) {
    int e = blockIdx.x * blockDim.x + threadIdx.x;
    if (e < NE) atomicAdd(&counts[rows[e]], 1);
}

__global__ void scan1_kernel(const int* __restrict__ counts, int* __restrict__ blockSums) {
    __shared__ int s[SCAN_B];
    int t = threadIdx.x;
    int v = blockIdx.x * SCAN_B + t;
    s[t] = (v < NV) ? counts[v] : 0;
    __syncthreads();
    for (int off = SCAN_B / 2; off > 0; off >>= 1) {
        if (t < off) s[t] += s[t + off];
        __syncthreads();
    }
    if (t == 0) blockSums[blockIdx.x] = s[0];
}

__global__ void scan2_kernel(int* __restrict__ blockSums, int nb) {
    __shared__ int s[512];
    int t = threadIdx.x;
    int val = (t < nb) ? blockSums[t] : 0;
    s[t] = val;
    __syncthreads();
    for (int off = 1; off < 512; off <<= 1) {
        int v2 = (t >= off) ? s[t - off] : 0;
        __syncthreads();
        s[t] += v2;
        __syncthreads();
    }
    if (t < nb) blockSums[t] = s[t] - val;  // exclusive
}

__global__ void scan3_kernel(const int* __restrict__ counts, const int* __restrict__ blockSums,
                             int* __restrict__ row_start, int* __restrict__ cursor) {
    __shared__ int s[SCAN_B];
    int t = threadIdx.x;
    int v = blockIdx.x * SCAN_B + t;
    int c = (v < NV) ? counts[v] : 0;
    s[t] = c;
    __syncthreads();
    for (int off = 1; off < SCAN_B; off <<= 1) {
        int v2 = (t >= off) ? s[t - off] : 0;
        __syncthreads();
        s[t] += v2;
        __syncthreads();
    }
    if (v < NV) {
        int st = blockSums[blockIdx.x] + s[t] - c;  // exclusive start
        row_start[v] = st;
        cursor[v] = st;
    }
}

__global__ void place_kernel(const int* __restrict__ rows, const int* __restrict__ cols,
                             const float* __restrict__ vals, int* __restrict__ cursor,
                             int* __restrict__ ecol, float* __restrict__ eval) {
    int e = blockIdx.x * blockDim.x + threadIdx.x;
    if (e >= NE) return;
    int r = rows[e];
    int pos = atomicAdd(&cursor[r], 1);
    ecol[pos] = cols[e];
    eval[pos] = vals[e];
}

// ---------------- gather SpMM with fused recursion ----------------
// one wave per row; lane = b*32 + f
// xnext[b,r,f] = alpha * sum_j val[j] * xcur[b, col[j], f]  +  beta * xprev[b,r,f]
__global__ void spmm_gather_kernel(float* __restrict__ xnext, const float* __restrict__ xcur,
                                   const float* __restrict__ xprev,
                                   const int* __restrict__ row_start, const int* __restrict__ counts,
                                   const int* __restrict__ ecol, const float* __restrict__ eval,
                                   float alpha, float beta) {
    int wave_in_blk = threadIdx.x >> 6;
    int r = blockIdx.x * (blockDim.x >> 6) + wave_in_blk;
    if (r >= NV) return;
    int lane = threadIdx.x & 63;
    int b = lane >> 5, f = lane & 31;
    const float* xb = xcur + (long)b * NV * FIN + f;
    int s = row_start[r];
    int cnt = counts[r];
    float acc = 0.f;
    int j = 0;
    for (; j + 2 <= cnt; j += 2) {
        int c0 = ecol[s + j], c1 = ecol[s + j + 1];
        float v0 = eval[s + j], v1 = eval[s + j + 1];
        float g0 = xb[(long)c0 * FIN];
        float g1 = xb[(long)c1 * FIN];
        acc += v0 * g0;
        acc += v1 * g1;
    }
    if (j < cnt) {
        int c0 = ecol[s + j];
        acc += eval[s + j] * xb[(long)c0 * FIN];
    }
    long o = (long)b * NV * FIN + (long)r * FIN + f;
    float res = alpha * acc;
    if (beta != 0.f) res += beta * xprev[o];
    xnext[o] = res;
}

// ---------------- per-term dense epilogue ----------------
__global__ void term_gemm_kernel(float* __restrict__ out, const float* __restrict__ x,
                                 const float* __restrict__ weight, const float* __restrict__ bias,
                                 int k, int first) {
    __shared__ float Wl[FIN][FOUT];
    __shared__ float Xl[8][FIN];
    int tid = threadIdx.x;
    for (int i = tid; i < FIN * FOUT; i += 256) {
        int f = i >> 5, o = i & 31;
        Wl[f][o] = weight[f * (NK * FOUT) + k * FOUT + o];
    }
    long rbase = (long)blockIdx.x * 8;
    for (int i = tid; i < 8 * FIN; i += 256) {
        int rv = i >> 5, f = i & 31;
        Xl[rv][f] = x[(rbase + rv) * FIN + f];
    }
    __syncthreads();
    int rv = tid >> 5, o = tid & 31;
    float acc = 0.f;
#pragma unroll
    for (int f = 0; f < FIN; ++f) acc += Xl[rv][f] * Wl[f][o];
    long r = rbase + rv;
    if (first) out[r * FOUT + o] = acc + bias[o];
    else       out[r * FOUT + o] += acc;
}

extern "C" void kernel_launch(void* const* d_in, const int* in_sizes, int n_in,
                              void* d_out, int out_size, void* d_ws, size_t ws_size,
                              hipStream_t stream) {
    const float* inputs = (const float*)d_in[0];   // [B, V, FIN]
    const int*   rows   = (const int*)d_in[1];     // [E]
    const int*   cols   = (const int*)d_in[2];     // [E]
    const float* vals   = (const float*)d_in[3];   // [E]
    const float* weight = (const float*)d_in[4];   // [FIN, K, FOUT]
    const float* bias   = (const float*)d_in[5];   // [FOUT]
    float* out = (float*)d_out;                    // [B, V, FOUT]

    const long n = (long)NB * NV * FIN;            // 6.4M floats
    const int gG = (NB * NV) / 8;                  // gemm grid
    const int gV = (NV + 255) / 256;               // 391
    const int gE = (NE + 255) / 256;               // 6250
    const int gRow = (NV + 3) / 4;                 // 25000 (4 waves/block)

    // ws layout: CSR area then two float buffers
    int* counts    = (int*)d_ws;
    int* row_start = counts + NV;
    int* cursor    = row_start + NV;
    int* blockSums = cursor + NV;
    int* ecol      = blockSums + 512;
    float* eval    = (float*)(ecol + NE);
    size_t off = (size_t)((char*)(eval + NE) - (char*)d_ws);
    off = (off + 255) & ~(size_t)255;
    float* bufA = (float*)((char*)d_ws + off);
    float* bufB = bufA + n;
    size_t need = off + 2 * (size_t)n * sizeof(float);

    if (ws_size < need) {
        // fallback: round-0 atomic scatter path (needs only 2*n floats)
        float* fA = (float*)d_ws;
        float* fB = fA + n;
        const int gNf = (int)((n + 255) / 256);
        const int gEf = (NE * 32 + 255) / 256;
        term_gemm_kernel<<<gG, 256, 0, stream>>>(out, inputs, weight, bias, 0, 1);
        scale_init_kernel<<<gNf, 256, 0, stream>>>(fA, inputs, 0.f, (int)n);
        spmm_scatter_kernel<<<gEf, 256, 0, stream>>>(fA, inputs, rows, cols, vals, 1.f);
        term_gemm_kernel<<<gG, 256, 0, stream>>>(out, fA, weight, bias, 1, 0);
        scale_init_kernel<<<gNf, 256, 0, stream>>>(fB, inputs, -1.f, (int)n);
        spmm_scatter_kernel<<<gEf, 256, 0, stream>>>(fB, fA, rows, cols, vals, 2.f);
        term_gemm_kernel<<<gG, 256, 0, stream>>>(out, fB, weight, bias, 2, 0);
        scale_init_kernel<<<gNf, 256, 0, stream>>>(fA, fA, -1.f, (int)n);
        spmm_scatter_kernel<<<gEf, 256, 0, stream>>>(fA, fB, rows, cols, vals, 2.f);
        term_gemm_kernel<<<gG, 256, 0, stream>>>(out, fA, weight, bias, 3, 0);
        return;
    }

    // term 0 epilogue (independent of CSR build)
    term_gemm_kernel<<<gG, 256, 0, stream>>>(out, inputs, weight, bias, 0, 1);

    // build CSR
    zero_counts_kernel<<<gV, 256, 0, stream>>>(counts);
    hist_kernel<<<gE, 256, 0, stream>>>(rows, counts);
    scan1_kernel<<<gV, SCAN_B, 0, stream>>>(counts, blockSums);
    scan2_kernel<<<1, 512, 0, stream>>>(blockSums, gV);
    scan3_kernel<<<gV, SCAN_B, 0, stream>>>(counts, blockSums, row_start, cursor);
    place_kernel<<<gE, 256, 0, stream>>>(rows, cols, vals, cursor, ecol, eval);

    // x1 = L x0
    spmm_gather_kernel<<<gRow, 256, 0, stream>>>(bufA, inputs, nullptr, row_start, counts,
                                                 ecol, eval, 1.f, 0.f);
    term_gemm_kernel<<<gG, 256, 0, stream>>>(out, bufA, weight, bias, 1, 0);

    // x2 = 2 L x1 - x0
    spmm_gather_kernel<<<gRow, 256, 0, stream>>>(bufB, bufA, inputs, row_start, counts,
                                                 ecol, eval, 2.f, -1.f);
    term_gemm_kernel<<<gG, 256, 0, stream>>>(out, bufB, weight, bias, 2, 0);

    // x3 = 2 L x2 - x1
    spmm_gather_kernel<<<gRow, 256, 0, stream>>>(bufA, bufB, bufA, row_start, counts,
                                                 ecol, eval, 2.f, -1.f);
    term_gemm_kernel<<<gG, 256, 0, stream>>>(out, bufA, weight, bias, 3, 0);
}

// Round 3
// 439.646 us; speedup vs baseline: 2.5425x; 1.3787x over previous
//
#include <hip/hip_runtime.h>
#include <hip/hip_bf16.h>

#define NV 100000
#define NE 1600000
#define NB 2
#define FIN 32
#define NK 4
#define FOUT 32
#define SCAN_B 256

typedef long long ll;

// ---------------- fallback (round-0) kernels ----------------

__global__ void scale_init_kernel(float* __restrict__ dst, const float* __restrict__ src,
                                  float alpha, int n) {
    int i = blockIdx.x * blockDim.x + threadIdx.x;
    if (i < n) dst[i] = alpha * src[i];
}

__global__ void spmm_scatter_kernel(float* __restrict__ y, const float* __restrict__ x,
                                    const int* __restrict__ rows, const int* __restrict__ cols,
                                    const float* __restrict__ vals, float scale) {
    long tid = (long)blockIdx.x * blockDim.x + threadIdx.x;
    int e = (int)(tid >> 5);
    int f = (int)(tid & 31);
    if (e >= NE) return;
    int r = rows[e];
    int c = cols[e];
    float v = scale * vals[e];
#pragma unroll
    for (int b = 0; b < NB; ++b) {
        float g = x[(long)b * NV * FIN + (long)c * FIN + f];
        atomicAdd(&y[(long)b * NV * FIN + (long)r * FIN + f], v * g);
    }
}

__global__ void term_gemm_kernel(float* __restrict__ out, const float* __restrict__ x,
                                 const float* __restrict__ weight, const float* __restrict__ bias,
                                 int k, int first) {
    __shared__ float Wl[FIN][FOUT];
    __shared__ float Xl[8][FIN];
    int tid = threadIdx.x;
    for (int i = tid; i < FIN * FOUT; i += 256) {
        int f = i >> 5, o = i & 31;
        Wl[f][o] = weight[f * (NK * FOUT) + k * FOUT + o];
    }
    long rbase = (long)blockIdx.x * 8;
    for (int i = tid; i < 8 * FIN; i += 256) {
        int rv = i >> 5, f = i & 31;
        Xl[rv][f] = x[(rbase + rv) * FIN + f];
    }
    __syncthreads();
    int rv = tid >> 5, o = tid & 31;
    float acc = 0.f;
#pragma unroll
    for (int f = 0; f < FIN; ++f) acc += Xl[rv][f] * Wl[f][o];
    long r = rbase + rv;
    if (first) out[r * FOUT + o] = acc + bias[o];
    else       out[r * FOUT + o] += acc;
}

// ---------------- CSR build ----------------

__global__ void hist_kernel(const int* __restrict__ rows, int* __restrict__ counts) {
    int e = blockIdx.x * blockDim.x + threadIdx.x;
    if (e < NE) atomicAdd(&counts[rows[e]], 1);
}

__global__ void scan1_kernel(const int* __restrict__ counts, int* __restrict__ blockSums) {
    __shared__ int s[SCAN_B];
    int t = threadIdx.x;
    int v = blockIdx.x * SCAN_B + t;
    s[t] = (v < NV) ? counts[v] : 0;
    __syncthreads();
    for (int off = SCAN_B / 2; off > 0; off >>= 1) {
        if (t < off) s[t] += s[t + off];
        __syncthreads();
    }
    if (t == 0) blockSums[blockIdx.x] = s[0];
}

__global__ void scan2_kernel(int* __restrict__ blockSums, int nb) {
    __shared__ int s[512];
    int t = threadIdx.x;
    int val = (t < nb) ? blockSums[t] : 0;
    s[t] = val;
    __syncthreads();
    for (int off = 1; off < 512; off <<= 1) {
        int v2 = (t >= off) ? s[t - off] : 0;
        __syncthreads();
        s[t] += v2;
        __syncthreads();
    }
    if (t < nb) blockSums[t] = s[t] - val;  // exclusive
}

__global__ void scan3_kernel(const int* __restrict__ counts, const int* __restrict__ blockSums,
                             int* __restrict__ row_start, int* __restrict__ cursor) {
    __shared__ int s[SCAN_B];
    int t = threadIdx.x;
    int v = blockIdx.x * SCAN_B + t;
    int c = (v < NV) ? counts[v] : 0;
    s[t] = c;
    __syncthreads();
    for (int off = 1; off < SCAN_B; off <<= 1) {
        int v2 = (t >= off) ? s[t - off] : 0;
        __syncthreads();
        s[t] += v2;
        __syncthreads();
    }
    if (v < NV) {
        int st = blockSums[blockIdx.x] + s[t] - c;  // exclusive start
        row_start[v] = st;
        cursor[v] = st;
    }
}

// one 8B record per edge: low 32 = col, high 32 = val bits
__global__ void place_kernel(const int* __restrict__ rows, const int* __restrict__ cols,
                             const float* __restrict__ vals, int* __restrict__ cursor,
                             ll* __restrict__ edges) {
    int e = blockIdx.x * blockDim.x + threadIdx.x;
    if (e >= NE) return;
    int r = rows[e];
    int pos = atomicAdd(&cursor[r], 1);
    unsigned int c = (unsigned int)cols[e];
    unsigned int vb = __float_as_uint(vals[e]);
    edges[pos] = (ll)c | ((ll)vb << 32);
}

// ---------------- bf16 conversion: inputs [B,V,F] -> xb [V, B*32] ----------------
__global__ void convert_x0_kernel(__hip_bfloat16* __restrict__ xb, const float* __restrict__ inputs) {
    long i = (long)blockIdx.x * blockDim.x + threadIdx.x;
    if (i >= (long)NV * 64) return;
    int lane = (int)(i & 63);
    long v = i >> 6;
    int b = lane >> 5, f = lane & 31;
    xb[i] = __float2bfloat16(inputs[(long)b * NV * FIN + v * FIN + f]);
}

// ---------------- gather SpMM with fused recursion (bf16) ----------------
// one wave per row; lane = b*32 + f; x layout [V, 64]
__global__ __launch_bounds__(256)
void spmm_gather_kernel(__hip_bfloat16* __restrict__ xnext, const __hip_bfloat16* __restrict__ xcur,
                        const __hip_bfloat16* __restrict__ xprev,
                        const int* __restrict__ row_start, const int* __restrict__ counts,
                        const ll* __restrict__ edges, float alpha, float beta) {
    int r = blockIdx.x * (blockDim.x >> 6) + (threadIdx.x >> 6);
    if (r >= NV) return;
    int lane = threadIdx.x & 63;
    int s = row_start[r];
    int cnt = counts[r];
    const ll* ep = edges + s;
    float acc = 0.f;
    int j = 0;
    for (; j + 4 <= cnt; j += 4) {
        ll e0 = ep[j], e1 = ep[j + 1], e2 = ep[j + 2], e3 = ep[j + 3];
        float g0 = __bfloat162float(xcur[(long)(int)e0 * 64 + lane]);
        float g1 = __bfloat162float(xcur[(long)(int)e1 * 64 + lane]);
        float g2 = __bfloat162float(xcur[(long)(int)e2 * 64 + lane]);
        float g3 = __bfloat162float(xcur[(long)(int)e3 * 64 + lane]);
        acc = fmaf(__uint_as_float((unsigned int)((unsigned long long)e0 >> 32)), g0, acc);
        acc = fmaf(__uint_as_float((unsigned int)((unsigned long long)e1 >> 32)), g1, acc);
        acc = fmaf(__uint_as_float((unsigned int)((unsigned long long)e2 >> 32)), g2, acc);
        acc = fmaf(__uint_as_float((unsigned int)((unsigned long long)e3 >> 32)), g3, acc);
    }
    for (; j < cnt; ++j) {
        ll e0 = ep[j];
        float g0 = __bfloat162float(xcur[(long)(int)e0 * 64 + lane]);
        acc = fmaf(__uint_as_float((unsigned int)((unsigned long long)e0 >> 32)), g0, acc);
    }
    long o = (long)r * 64 + lane;
    float res = alpha * acc;
    if (beta != 0.f) res += beta * __bfloat162float(xprev[o]);
    xnext[o] = __float2bfloat16(res);
}

// ---------------- fused final einsum: out = bias + sum_k xk @ W[:,k,:] ----------------
// thread = (v, b); acc[32] in VGPRs; W loads are wave-uniform -> scalar loads
__global__ __launch_bounds__(256)
void final_gemm_kernel(float* __restrict__ out,
                       const __hip_bfloat16* __restrict__ xb0,
                       const __hip_bfloat16* __restrict__ xb1,
                       const __hip_bfloat16* __restrict__ xb2,
                       const __hip_bfloat16* __restrict__ xb3,
                       const float* __restrict__ weight,
                       const float* __restrict__ bias) {
    int t = blockIdx.x * blockDim.x + threadIdx.x;
    if (t >= NV * NB) return;
    int v = t >> 1, b = t & 1;
    float acc[FOUT];
#pragma unroll
    for (int o = 0; o < FOUT; ++o) acc[o] = bias[o];
    for (int k = 0; k < NK; ++k) {
        const __hip_bfloat16* xr = (k == 0) ? xb0 : (k == 1) ? xb1 : (k == 2) ? xb2 : xb3;
        const uint4* xp = (const uint4*)(xr + (long)v * 64 + b * 32);
        uint4 q0 = xp[0], q1 = xp[1], q2 = xp[2], q3 = xp[3];
        unsigned int qq[16] = {q0.x, q0.y, q0.z, q0.w, q1.x, q1.y, q1.z, q1.w,
                               q2.x, q2.y, q2.z, q2.w, q3.x, q3.y, q3.z, q3.w};
        const float* wk = weight + k * FOUT;
#pragma unroll
        for (int i = 0; i < 16; ++i) {
            float xlo = __uint_as_float(qq[i] << 16);           // f = 2i   (bf16 -> f32 is a shift)
            float xhi = __uint_as_float(qq[i] & 0xffff0000u);   // f = 2i+1
            const float* w0 = wk + (2 * i) * (NK * FOUT);
            const float* w1 = wk + (2 * i + 1) * (NK * FOUT);
#pragma unroll
            for (int o = 0; o < FOUT; ++o) {
                acc[o] = fmaf(xlo, w0[o], acc[o]);
                acc[o] = fmaf(xhi, w1[o], acc[o]);
            }
        }
    }
    float* op = out + (long)b * NV * FOUT + (long)v * FOUT;
#pragma unroll
    for (int o = 0; o < FOUT; ++o) op[o] = acc[o];
}

extern "C" void kernel_launch(void* const* d_in, const int* in_sizes, int n_in,
                              void* d_out, int out_size, void* d_ws, size_t ws_size,
                              hipStream_t stream) {
    const float* inputs = (const float*)d_in[0];
    const int*   rows   = (const int*)d_in[1];
    const int*   cols   = (const int*)d_in[2];
    const float* vals   = (const float*)d_in[3];
    const float* weight = (const float*)d_in[4];
    const float* bias   = (const float*)d_in[5];
    float* out = (float*)d_out;

    const long n = (long)NB * NV * FIN;            // 6.4M
    const int gG = (NB * NV) / 8;
    const int gV = (NV + SCAN_B - 1) / SCAN_B;     // 391
    const int gE = (NE + 255) / 256;               // 6250
    const int gRow = (NV + 3) / 4;                 // 25000
    const int gConv = (int)(((long)NV * 64 + 255) / 256);
    const int gGemm = (NV * NB + 255) / 256;       // 782

    // ws layout
    int* counts    = (int*)d_ws;
    int* row_start = counts + NV;
    int* cursor    = row_start + NV;
    int* blockSums = cursor + NV;
    ll* edges      = (ll*)(blockSums + 512);       // 8B-aligned (3*NV+512 ints)
    size_t off = (size_t)((char*)(edges + NE) - (char*)d_ws);
    off = (off + 255) & ~(size_t)255;
    __hip_bfloat16* xb0 = (__hip_bfloat16*)((char*)d_ws + off);
    __hip_bfloat16* xb1 = xb0 + (long)NV * 64;
    __hip_bfloat16* xb2 = xb1 + (long)NV * 64;
    __hip_bfloat16* xb3 = xb2 + (long)NV * 64;
    size_t need = off + 4 * (size_t)NV * 64 * sizeof(__hip_bfloat16);

    if (ws_size < need) {
        // fallback: round-0 atomic scatter path
        float* fA = (float*)d_ws;
        float* fB = fA + n;
        const int gNf = (int)((n + 255) / 256);
        const int gEf = (NE * 32 + 255) / 256;
        term_gemm_kernel<<<gG, 256, 0, stream>>>(out, inputs, weight, bias, 0, 1);
        scale_init_kernel<<<gNf, 256, 0, stream>>>(fA, inputs, 0.f, (int)n);
        spmm_scatter_kernel<<<gEf, 256, 0, stream>>>(fA, inputs, rows, cols, vals, 1.f);
        term_gemm_kernel<<<gG, 256, 0, stream>>>(out, fA, weight, bias, 1, 0);
        scale_init_kernel<<<gNf, 256, 0, stream>>>(fB, inputs, -1.f, (int)n);
        spmm_scatter_kernel<<<gEf, 256, 0, stream>>>(fB, fA, rows, cols, vals, 2.f);
        term_gemm_kernel<<<gG, 256, 0, stream>>>(out, fB, weight, bias, 2, 0);
        scale_init_kernel<<<gNf, 256, 0, stream>>>(fA, fA, -1.f, (int)n);
        spmm_scatter_kernel<<<gEf, 256, 0, stream>>>(fA, fB, rows, cols, vals, 2.f);
        term_gemm_kernel<<<gG, 256, 0, stream>>>(out, fA, weight, bias, 3, 0);
        return;
    }

    // CSR build
    hipMemsetAsync(counts, 0, (size_t)NV * sizeof(int), stream);
    hist_kernel<<<gE, 256, 0, stream>>>(rows, counts);
    scan1_kernel<<<gV, SCAN_B, 0, stream>>>(counts, blockSums);
    scan2_kernel<<<1, 512, 0, stream>>>(blockSums, gV);
    scan3_kernel<<<gV, SCAN_B, 0, stream>>>(counts, blockSums, row_start, cursor);
    place_kernel<<<gE, 256, 0, stream>>>(rows, cols, vals, cursor, edges);

    // x0 -> bf16 [V, 64]
    convert_x0_kernel<<<gConv, 256, 0, stream>>>(xb0, inputs);

    // recursion
    spmm_gather_kernel<<<gRow, 256, 0, stream>>>(xb1, xb0, nullptr, row_start, counts,
                                                 edges, 1.f, 0.f);
    spmm_gather_kernel<<<gRow, 256, 0, stream>>>(xb2, xb1, xb0, row_start, counts,
                                                 edges, 2.f, -1.f);
    spmm_gather_kernel<<<gRow, 256, 0, stream>>>(xb3, xb2, xb1, row_start, counts,
                                                 edges, 2.f, -1.f);

    // fused einsum over all 4 terms
    final_gemm_kernel<<<gGemm, 256, 0, stream>>>(out, xb0, xb1, xb2, xb3, weight, bias);
}

// Round 4
// 304.471 us; speedup vs baseline: 3.6713x; 1.4440x over previous
//
#include <hip/hip_runtime.h>
#include <hip/hip_bf16.h>

#define NV 100000
#define NE 1600000
#define NB 2
#define FIN 32
#define NK 4
#define FOUT 32

#define RPB 128                          // rows per bucket
#define NBUCK ((NV + RPB - 1) / RPB)     // 782
#define CHUNK 8192                       // edges per block in bucket passes

typedef long long ll;

// ---------------- fallback (round-0) kernels ----------------

__global__ void scale_init_kernel(float* __restrict__ dst, const float* __restrict__ src,
                                  float alpha, int n) {
    int i = blockIdx.x * blockDim.x + threadIdx.x;
    if (i < n) dst[i] = alpha * src[i];
}

__global__ void spmm_scatter_kernel(float* __restrict__ y, const float* __restrict__ x,
                                    const int* __restrict__ rows, const int* __restrict__ cols,
                                    const float* __restrict__ vals, float scale) {
    long tid = (long)blockIdx.x * blockDim.x + threadIdx.x;
    int e = (int)(tid >> 5);
    int f = (int)(tid & 31);
    if (e >= NE) return;
    int r = rows[e];
    int c = cols[e];
    float v = scale * vals[e];
#pragma unroll
    for (int b = 0; b < NB; ++b) {
        float g = x[(long)b * NV * FIN + (long)c * FIN + f];
        atomicAdd(&y[(long)b * NV * FIN + (long)r * FIN + f], v * g);
    }
}

__global__ void term_gemm_kernel(float* __restrict__ out, const float* __restrict__ x,
                                 const float* __restrict__ weight, const float* __restrict__ bias,
                                 int k, int first) {
    __shared__ float Wl[FIN][FOUT];
    __shared__ float Xl[8][FIN];
    int tid = threadIdx.x;
    for (int i = tid; i < FIN * FOUT; i += 256) {
        int f = i >> 5, o = i & 31;
        Wl[f][o] = weight[f * (NK * FOUT) + k * FOUT + o];
    }
    long rbase = (long)blockIdx.x * 8;
    for (int i = tid; i < 8 * FIN; i += 256) {
        int rv = i >> 5, f = i & 31;
        Xl[rv][f] = x[(rbase + rv) * FIN + f];
    }
    __syncthreads();
    int rv = tid >> 5, o = tid & 31;
    float acc = 0.f;
#pragma unroll
    for (int f = 0; f < FIN; ++f) acc += Xl[rv][f] * Wl[f][o];
    long r = rbase + rv;
    if (first) out[r * FOUT + o] = acc + bias[o];
    else       out[r * FOUT + o] += acc;
}

// ---------------- hierarchical CSR build ----------------
// edge record (8B): bits 0..16 = col, bits 17..23 = row-within-bucket, high 32 = val bits

__global__ __launch_bounds__(256)
void bucket_hist_kernel(const int* __restrict__ rows, int* __restrict__ bcount) {
    __shared__ int cnt[NBUCK];
    for (int i = threadIdx.x; i < NBUCK; i += 256) cnt[i] = 0;
    __syncthreads();
    long base = (long)blockIdx.x * CHUNK;
    int lim = (base + CHUNK <= NE) ? CHUNK : (int)(NE - base);
    for (int i = threadIdx.x; i < lim; i += 256)
        atomicAdd(&cnt[rows[base + i] >> 7], 1);
    __syncthreads();
    for (int i = threadIdx.x; i < NBUCK; i += 256)
        if (cnt[i]) atomicAdd(&bcount[i], cnt[i]);
}

__global__ __launch_bounds__(1024)
void bucket_scan_kernel(const int* __restrict__ bcount, int* __restrict__ bstart,
                        int* __restrict__ gcursor) {
    __shared__ int s[1024];
    int t = threadIdx.x;
    int v = (t < NBUCK) ? bcount[t] : 0;
    s[t] = v;
    __syncthreads();
    for (int off = 1; off < 1024; off <<= 1) {
        int x = (t >= off) ? s[t - off] : 0;
        __syncthreads();
        s[t] += x;
        __syncthreads();
    }
    if (t < NBUCK) {
        int st = s[t] - v;   // exclusive
        bstart[t] = st;
        gcursor[t] = st;
    }
}

__global__ __launch_bounds__(256)
void bucket_place_kernel(const int* __restrict__ rows, const int* __restrict__ cols,
                         const float* __restrict__ vals, int* __restrict__ gcursor,
                         ll* __restrict__ edges_tmp) {
    __shared__ int cnt[NBUCK];
    __shared__ int cur[NBUCK];
    for (int i = threadIdx.x; i < NBUCK; i += 256) cnt[i] = 0;
    __syncthreads();
    long base = (long)blockIdx.x * CHUNK;
    int lim = (base + CHUNK <= NE) ? CHUNK : (int)(NE - base);
    for (int i = threadIdx.x; i < lim; i += 256)
        atomicAdd(&cnt[rows[base + i] >> 7], 1);
    __syncthreads();
    // reserve a contiguous range per bucket for this block
    for (int i = threadIdx.x; i < NBUCK; i += 256)
        cur[i] = cnt[i] ? atomicAdd(&gcursor[i], cnt[i]) : 0;
    __syncthreads();
    for (int i = threadIdx.x; i < lim; i += 256) {
        int r = rows[base + i];
        int b = r >> 7;
        unsigned int lo = ((unsigned int)cols[base + i]) | (((unsigned int)(r & 127)) << 17);
        unsigned int hi = __float_as_uint(vals[base + i]);
        int pos = atomicAdd(&cur[b], 1);
        edges_tmp[pos] = (ll)lo | ((ll)hi << 32);
    }
}

__global__ __launch_bounds__(256)
void bucket_sort_kernel(const ll* __restrict__ edges_tmp, ll* __restrict__ edges,
                        const int* __restrict__ bstart, const int* __restrict__ bcount,
                        int* __restrict__ row_start, int* __restrict__ counts) {
    __shared__ int rcnt[RPB];
    __shared__ int rcur[RPB];
    __shared__ int s[RPB];
    int b = blockIdx.x;
    int base = bstart[b];
    int n = bcount[b];
    int t = threadIdx.x;
    if (t < RPB) rcnt[t] = 0;
    __syncthreads();
    for (int i = t; i < n; i += 256) {
        int lr = (int)(((unsigned long long)edges_tmp[base + i] >> 17) & 127);
        atomicAdd(&rcnt[lr], 1);
    }
    __syncthreads();
    if (t < RPB) s[t] = rcnt[t];
    __syncthreads();
    for (int off = 1; off < RPB; off <<= 1) {
        int x = 0;
        if (t < RPB && t >= off) x = s[t - off];
        __syncthreads();
        if (t < RPB) s[t] += x;
        __syncthreads();
    }
    if (t < RPB) {
        int ex = s[t] - rcnt[t];          // exclusive scan
        rcur[t] = base + ex;
        int v = b * RPB + t;
        if (v < NV) { row_start[v] = base + ex; counts[v] = rcnt[t]; }
    }
    __syncthreads();
    for (int i = t; i < n; i += 256) {
        ll rec = edges_tmp[base + i];
        int lr = (int)(((unsigned long long)rec >> 17) & 127);
        int pos = atomicAdd(&rcur[lr], 1);
        edges[pos] = rec;
    }
}

// ---------------- bf16 conversion: inputs [B,V,F] -> xb [V, B*32] ----------------
__global__ void convert_x0_kernel(__hip_bfloat16* __restrict__ xb, const float* __restrict__ inputs) {
    long i = (long)blockIdx.x * blockDim.x + threadIdx.x;
    if (i >= (long)NV * 64) return;
    int lane = (int)(i & 63);
    long v = i >> 6;
    int b = lane >> 5, f = lane & 31;
    xb[i] = __float2bfloat16(inputs[(long)b * NV * FIN + v * FIN + f]);
}

// ---------------- gather SpMM with fused recursion (bf16) ----------------
// one wave per row; lane = b*32 + f; x layout [V, 64]
__global__ __launch_bounds__(256)
void spmm_gather_kernel(__hip_bfloat16* __restrict__ xnext, const __hip_bfloat16* __restrict__ xcur,
                        const __hip_bfloat16* __restrict__ xprev,
                        const int* __restrict__ row_start, const int* __restrict__ counts,
                        const ll* __restrict__ edges, float alpha, float beta) {
    int r = blockIdx.x * (blockDim.x >> 6) + (threadIdx.x >> 6);
    if (r >= NV) return;
    int lane = threadIdx.x & 63;
    int s = row_start[r];
    int cnt = counts[r];
    const ll* ep = edges + s;
    float acc = 0.f;
    int j = 0;
    for (; j + 4 <= cnt; j += 4) {
        ll e0 = ep[j], e1 = ep[j + 1], e2 = ep[j + 2], e3 = ep[j + 3];
        float g0 = __bfloat162float(xcur[(long)(e0 & 0x1FFFF) * 64 + lane]);
        float g1 = __bfloat162float(xcur[(long)(e1 & 0x1FFFF) * 64 + lane]);
        float g2 = __bfloat162float(xcur[(long)(e2 & 0x1FFFF) * 64 + lane]);
        float g3 = __bfloat162float(xcur[(long)(e3 & 0x1FFFF) * 64 + lane]);
        acc = fmaf(__uint_as_float((unsigned int)((unsigned long long)e0 >> 32)), g0, acc);
        acc = fmaf(__uint_as_float((unsigned int)((unsigned long long)e1 >> 32)), g1, acc);
        acc = fmaf(__uint_as_float((unsigned int)((unsigned long long)e2 >> 32)), g2, acc);
        acc = fmaf(__uint_as_float((unsigned int)((unsigned long long)e3 >> 32)), g3, acc);
    }
    for (; j < cnt; ++j) {
        ll e0 = ep[j];
        float g0 = __bfloat162float(xcur[(long)(e0 & 0x1FFFF) * 64 + lane]);
        acc = fmaf(__uint_as_float((unsigned int)((unsigned long long)e0 >> 32)), g0, acc);
    }
    long o = (long)r * 64 + lane;
    float res = alpha * acc;
    if (beta != 0.f) res += beta * __bfloat162float(xprev[o]);
    xnext[o] = __float2bfloat16(res);
}

// ---------------- fused final einsum: out = bias + sum_k xk @ W[:,k,:] ----------------
__global__ __launch_bounds__(256)
void final_gemm_kernel(float* __restrict__ out,
                       const __hip_bfloat16* __restrict__ xb0,
                       const __hip_bfloat16* __restrict__ xb1,
                       const __hip_bfloat16* __restrict__ xb2,
                       const __hip_bfloat16* __restrict__ xb3,
                       const float* __restrict__ weight,
                       const float* __restrict__ bias) {
    int t = blockIdx.x * blockDim.x + threadIdx.x;
    if (t >= NV * NB) return;
    int v = t >> 1, b = t & 1;
    float acc[FOUT];
#pragma unroll
    for (int o = 0; o < FOUT; ++o) acc[o] = bias[o];
    for (int k = 0; k < NK; ++k) {
        const __hip_bfloat16* xr = (k == 0) ? xb0 : (k == 1) ? xb1 : (k == 2) ? xb2 : xb3;
        const uint4* xp = (const uint4*)(xr + (long)v * 64 + b * 32);
        uint4 q0 = xp[0], q1 = xp[1], q2 = xp[2], q3 = xp[3];
        unsigned int qq[16] = {q0.x, q0.y, q0.z, q0.w, q1.x, q1.y, q1.z, q1.w,
                               q2.x, q2.y, q2.z, q2.w, q3.x, q3.y, q3.z, q3.w};
        const float* wk = weight + k * FOUT;
#pragma unroll
        for (int i = 0; i < 16; ++i) {
            float xlo = __uint_as_float(qq[i] << 16);
            float xhi = __uint_as_float(qq[i] & 0xffff0000u);
            const float* w0 = wk + (2 * i) * (NK * FOUT);
            const float* w1 = wk + (2 * i + 1) * (NK * FOUT);
#pragma unroll
            for (int o = 0; o < FOUT; ++o) {
                acc[o] = fmaf(xlo, w0[o], acc[o]);
                acc[o] = fmaf(xhi, w1[o], acc[o]);
            }
        }
    }
    float* op = out + (long)b * NV * FOUT + (long)v * FOUT;
#pragma unroll
    for (int o = 0; o < FOUT; ++o) op[o] = acc[o];
}

extern "C" void kernel_launch(void* const* d_in, const int* in_sizes, int n_in,
                              void* d_out, int out_size, void* d_ws, size_t ws_size,
                              hipStream_t stream) {
    const float* inputs = (const float*)d_in[0];
    const int*   rows   = (const int*)d_in[1];
    const int*   cols   = (const int*)d_in[2];
    const float* vals   = (const float*)d_in[3];
    const float* weight = (const float*)d_in[4];
    const float* bias   = (const float*)d_in[5];
    float* out = (float*)d_out;

    const long n = (long)NB * NV * FIN;            // 6.4M
    const int gG = (NB * NV) / 8;
    const int gChunk = (NE + CHUNK - 1) / CHUNK;   // 196
    const int gRow = (NV + 3) / 4;                 // 25000
    const int gConv = (int)(((long)NV * 64 + 255) / 256);
    const int gGemm = (NV * NB + 255) / 256;       // 782

    // ws layout
    int* bcount    = (int*)d_ws;                   // [1024]
    int* bstart    = bcount + 1024;                // [1024]
    int* gcursor   = bstart + 1024;                // [1024]
    int* row_start = gcursor + 1024;               // [NV]
    int* counts    = row_start + NV;               // [NV]
    ll* edges      = (ll*)(counts + NV);           // [NE], 8B-aligned (3*1024+2*NV ints)
    size_t off = (size_t)((char*)(edges + NE) - (char*)d_ws);
    off = (off + 255) & ~(size_t)255;
    __hip_bfloat16* xb0 = (__hip_bfloat16*)((char*)d_ws + off);
    __hip_bfloat16* xb1 = xb0 + (long)NV * 64;
    __hip_bfloat16* xb2 = xb1 + (long)NV * 64;
    __hip_bfloat16* xb3 = xb2 + (long)NV * 64;
    ll* edges_tmp = (ll*)xb3;                      // aliases xb3: tmp dead before gather-3 writes xb3
    size_t need = off + 4 * (size_t)NV * 64 * sizeof(__hip_bfloat16);

    if (ws_size < need) {
        // fallback: round-0 atomic scatter path
        float* fA = (float*)d_ws;
        float* fB = fA + n;
        const int gNf = (int)((n + 255) / 256);
        const int gEf = (NE * 32 + 255) / 256;
        term_gemm_kernel<<<gG, 256, 0, stream>>>(out, inputs, weight, bias, 0, 1);
        scale_init_kernel<<<gNf, 256, 0, stream>>>(fA, inputs, 0.f, (int)n);
        spmm_scatter_kernel<<<gEf, 256, 0, stream>>>(fA, inputs, rows, cols, vals, 1.f);
        term_gemm_kernel<<<gG, 256, 0, stream>>>(out, fA, weight, bias, 1, 0);
        scale_init_kernel<<<gNf, 256, 0, stream>>>(fB, inputs, -1.f, (int)n);
        spmm_scatter_kernel<<<gEf, 256, 0, stream>>>(fB, fA, rows, cols, vals, 2.f);
        term_gemm_kernel<<<gG, 256, 0, stream>>>(out, fB, weight, bias, 2, 0);
        scale_init_kernel<<<gNf, 256, 0, stream>>>(fA, fA, -1.f, (int)n);
        spmm_scatter_kernel<<<gEf, 256, 0, stream>>>(fA, fB, rows, cols, vals, 2.f);
        term_gemm_kernel<<<gG, 256, 0, stream>>>(out, fA, weight, bias, 3, 0);
        return;
    }

    // hierarchical CSR build
    hipMemsetAsync(bcount, 0, (size_t)NBUCK * sizeof(int), stream);
    bucket_hist_kernel<<<gChunk, 256, 0, stream>>>(rows, bcount);
    bucket_scan_kernel<<<1, 1024, 0, stream>>>(bcount, bstart, gcursor);
    bucket_place_kernel<<<gChunk, 256, 0, stream>>>(rows, cols, vals, gcursor, edges_tmp);
    bucket_sort_kernel<<<NBUCK, 256, 0, stream>>>(edges_tmp, edges, bstart, bcount,
                                                  row_start, counts);

    // x0 -> bf16 [V, 64]
    convert_x0_kernel<<<gConv, 256, 0, stream>>>(xb0, inputs);

    // recursion
    spmm_gather_kernel<<<gRow, 256, 0, stream>>>(xb1, xb0, nullptr, row_start, counts,
                                                 edges, 1.f, 0.f);
    spmm_gather_kernel<<<gRow, 256, 0, stream>>>(xb2, xb1, xb0, row_start, counts,
                                                 edges, 2.f, -1.f);
    spmm_gather_kernel<<<gRow, 256, 0, stream>>>(xb3, xb2, xb1, row_start, counts,
                                                 edges, 2.f, -1.f);

    // fused einsum over all 4 terms
    final_gemm_kernel<<<gGemm, 256, 0, stream>>>(out, xb0, xb1, xb2, xb3, weight, bias);
}

// Round 5
// 278.166 us; speedup vs baseline: 4.0184x; 1.0946x over previous
//
#include <hip/hip_runtime.h>
#include <hip/hip_bf16.h>

#define NV 100000
#define NE 1600000
#define NB 2
#define FIN 32
#define NK 4
#define FOUT 32

#define RPB 128                          // rows per bucket
#define NBUCK ((NV + RPB - 1) / RPB)     // 782
#define CHUNK 8192                       // edges per block in bucket passes

typedef long long ll;

// ---------------- fallback (round-0) kernels ----------------

__global__ void scale_init_kernel(float* __restrict__ dst, const float* __restrict__ src,
                                  float alpha, int n) {
    int i = blockIdx.x * blockDim.x + threadIdx.x;
    if (i < n) dst[i] = alpha * src[i];
}

__global__ void spmm_scatter_kernel(float* __restrict__ y, const float* __restrict__ x,
                                    const int* __restrict__ rows, const int* __restrict__ cols,
                                    const float* __restrict__ vals, float scale) {
    long tid = (long)blockIdx.x * blockDim.x + threadIdx.x;
    int e = (int)(tid >> 5);
    int f = (int)(tid & 31);
    if (e >= NE) return;
    int r = rows[e];
    int c = cols[e];
    float v = scale * vals[e];
#pragma unroll
    for (int b = 0; b < NB; ++b) {
        float g = x[(long)b * NV * FIN + (long)c * FIN + f];
        atomicAdd(&y[(long)b * NV * FIN + (long)r * FIN + f], v * g);
    }
}

__global__ void term_gemm_kernel(float* __restrict__ out, const float* __restrict__ x,
                                 const float* __restrict__ weight, const float* __restrict__ bias,
                                 int k, int first) {
    __shared__ float Wl[FIN][FOUT];
    __shared__ float Xl[8][FIN];
    int tid = threadIdx.x;
    for (int i = tid; i < FIN * FOUT; i += 256) {
        int f = i >> 5, o = i & 31;
        Wl[f][o] = weight[f * (NK * FOUT) + k * FOUT + o];
    }
    long rbase = (long)blockIdx.x * 8;
    for (int i = tid; i < 8 * FIN; i += 256) {
        int rv = i >> 5, f = i & 31;
        Xl[rv][f] = x[(rbase + rv) * FIN + f];
    }
    __syncthreads();
    int rv = tid >> 5, o = tid & 31;
    float acc = 0.f;
#pragma unroll
    for (int f = 0; f < FIN; ++f) acc += Xl[rv][f] * Wl[f][o];
    long r = rbase + rv;
    if (first) out[r * FOUT + o] = acc + bias[o];
    else       out[r * FOUT + o] += acc;
}

// ---------------- hierarchical CSR build ----------------
// edge record (8B): bits 0..16 = col, bits 17..23 = row-within-bucket, high 32 = val bits

__global__ __launch_bounds__(256)
void bucket_hist_kernel(const int* __restrict__ rows, int* __restrict__ bcount) {
    __shared__ int cnt[NBUCK];
    for (int i = threadIdx.x; i < NBUCK; i += 256) cnt[i] = 0;
    __syncthreads();
    long base = (long)blockIdx.x * CHUNK;
    int lim = (base + CHUNK <= NE) ? CHUNK : (int)(NE - base);
    for (int i = threadIdx.x; i < lim; i += 256)
        atomicAdd(&cnt[rows[base + i] >> 7], 1);
    __syncthreads();
    for (int i = threadIdx.x; i < NBUCK; i += 256)
        if (cnt[i]) atomicAdd(&bcount[i], cnt[i]);
}

__global__ __launch_bounds__(1024)
void bucket_scan_kernel(const int* __restrict__ bcount, int* __restrict__ bstart,
                        int* __restrict__ gcursor) {
    __shared__ int s[1024];
    int t = threadIdx.x;
    int v = (t < NBUCK) ? bcount[t] : 0;
    s[t] = v;
    __syncthreads();
    for (int off = 1; off < 1024; off <<= 1) {
        int x = (t >= off) ? s[t - off] : 0;
        __syncthreads();
        s[t] += x;
        __syncthreads();
    }
    if (t < NBUCK) {
        int st = s[t] - v;   // exclusive
        bstart[t] = st;
        gcursor[t] = st;
    }
}

__global__ __launch_bounds__(256)
void bucket_place_kernel(const int* __restrict__ rows, const int* __restrict__ cols,
                         const float* __restrict__ vals, int* __restrict__ gcursor,
                         ll* __restrict__ edges_tmp) {
    __shared__ int cnt[NBUCK];
    __shared__ int cur[NBUCK];
    for (int i = threadIdx.x; i < NBUCK; i += 256) cnt[i] = 0;
    __syncthreads();
    long base = (long)blockIdx.x * CHUNK;
    int lim = (base + CHUNK <= NE) ? CHUNK : (int)(NE - base);
    for (int i = threadIdx.x; i < lim; i += 256)
        atomicAdd(&cnt[rows[base + i] >> 7], 1);
    __syncthreads();
    // reserve a contiguous range per bucket for this block
    for (int i = threadIdx.x; i < NBUCK; i += 256)
        cur[i] = cnt[i] ? atomicAdd(&gcursor[i], cnt[i]) : 0;
    __syncthreads();
    for (int i = threadIdx.x; i < lim; i += 256) {
        int r = rows[base + i];
        int b = r >> 7;
        unsigned int lo = ((unsigned int)cols[base + i]) | (((unsigned int)(r & 127)) << 17);
        unsigned int hi = __float_as_uint(vals[base + i]);
        int pos = atomicAdd(&cur[b], 1);
        edges_tmp[pos] = (ll)lo | ((ll)hi << 32);
    }
}

__global__ __launch_bounds__(256)
void bucket_sort_kernel(const ll* __restrict__ edges_tmp, ll* __restrict__ edges,
                        const int* __restrict__ bstart, const int* __restrict__ bcount,
                        int* __restrict__ row_start, int* __restrict__ counts) {
    __shared__ int rcnt[RPB];
    __shared__ int rcur[RPB];
    __shared__ int s[RPB];
    int b = blockIdx.x;
    int base = bstart[b];
    int n = bcount[b];
    int t = threadIdx.x;
    if (t < RPB) rcnt[t] = 0;
    __syncthreads();
    for (int i = t; i < n; i += 256) {
        int lr = (int)(((unsigned long long)edges_tmp[base + i] >> 17) & 127);
        atomicAdd(&rcnt[lr], 1);
    }
    __syncthreads();
    if (t < RPB) s[t] = rcnt[t];
    __syncthreads();
    for (int off = 1; off < RPB; off <<= 1) {
        int x = 0;
        if (t < RPB && t >= off) x = s[t - off];
        __syncthreads();
        if (t < RPB) s[t] += x;
        __syncthreads();
    }
    if (t < RPB) {
        int ex = s[t] - rcnt[t];          // exclusive scan
        rcur[t] = base + ex;
        int v = b * RPB + t;
        if (v < NV) { row_start[v] = base + ex; counts[v] = rcnt[t]; }
    }
    __syncthreads();
    for (int i = t; i < n; i += 256) {
        ll rec = edges_tmp[base + i];
        int lr = (int)(((unsigned long long)rec >> 17) & 127);
        int pos = atomicAdd(&rcur[lr], 1);
        edges[pos] = rec;
    }
}

// ---------------- bf16 conversion: inputs [B,V,F] -> xb [V, B*32] ----------------
__global__ void convert_x0_kernel(__hip_bfloat16* __restrict__ xb, const float* __restrict__ inputs) {
    long i = (long)blockIdx.x * blockDim.x + threadIdx.x;
    if (i >= (long)NV * 64) return;
    int lane = (int)(i & 63);
    long v = i >> 6;
    int b = lane >> 5, f = lane & 31;
    xb[i] = __float2bfloat16(inputs[(long)b * NV * FIN + v * FIN + f]);
}

// ---------------- gather SpMM with fused recursion (bf16) ----------------
// one wave per row; lane = b*32 + f; x layout [V, 64]
// deep-MLP inner loop: 8 edge records preloaded, 8 gathers in flight
__global__ __launch_bounds__(256)
void spmm_gather_kernel(__hip_bfloat16* __restrict__ xnext, const __hip_bfloat16* __restrict__ xcur,
                        const __hip_bfloat16* __restrict__ xprev,
                        const int* __restrict__ row_start, const int* __restrict__ counts,
                        const ll* __restrict__ edges, float alpha, float beta) {
    int r = blockIdx.x * (blockDim.x >> 6) + (threadIdx.x >> 6);
    if (r >= NV) return;
    int lane = threadIdx.x & 63;
    int s = row_start[r];
    int cnt = counts[r];
    const ll* ep = edges + s;
    float acc = 0.f;
    int j = 0;
    for (; j + 8 <= cnt; j += 8) {
        ll e[8];
#pragma unroll
        for (int u = 0; u < 8; ++u) e[u] = ep[j + u];
        float g[8];
#pragma unroll
        for (int u = 0; u < 8; ++u)
            g[u] = __bfloat162float(xcur[(long)(e[u] & 0x1FFFF) * 64 + lane]);
#pragma unroll
        for (int u = 0; u < 8; ++u)
            acc = fmaf(__uint_as_float((unsigned int)((unsigned long long)e[u] >> 32)), g[u], acc);
    }
    if (j + 4 <= cnt) {
        ll e[4];
#pragma unroll
        for (int u = 0; u < 4; ++u) e[u] = ep[j + u];
        float g[4];
#pragma unroll
        for (int u = 0; u < 4; ++u)
            g[u] = __bfloat162float(xcur[(long)(e[u] & 0x1FFFF) * 64 + lane]);
#pragma unroll
        for (int u = 0; u < 4; ++u)
            acc = fmaf(__uint_as_float((unsigned int)((unsigned long long)e[u] >> 32)), g[u], acc);
        j += 4;
    }
    for (; j < cnt; ++j) {
        ll e0 = ep[j];
        float g0 = __bfloat162float(xcur[(long)(e0 & 0x1FFFF) * 64 + lane]);
        acc = fmaf(__uint_as_float((unsigned int)((unsigned long long)e0 >> 32)), g0, acc);
    }
    long o = (long)r * 64 + lane;
    float res = alpha * acc;
    if (beta != 0.f) res += beta * __bfloat162float(xprev[o]);
    xnext[o] = __float2bfloat16(res);
}

// ---------------- fused final einsum: out = bias + sum_k xk @ W[:,k,:] ----------------
__global__ __launch_bounds__(256)
void final_gemm_kernel(float* __restrict__ out,
                       const __hip_bfloat16* __restrict__ xb0,
                       const __hip_bfloat16* __restrict__ xb1,
                       const __hip_bfloat16* __restrict__ xb2,
                       const __hip_bfloat16* __restrict__ xb3,
                       const float* __restrict__ weight,
                       const float* __restrict__ bias) {
    int t = blockIdx.x * blockDim.x + threadIdx.x;
    if (t >= NV * NB) return;
    int v = t >> 1, b = t & 1;
    float acc[FOUT];
#pragma unroll
    for (int o = 0; o < FOUT; ++o) acc[o] = bias[o];
    for (int k = 0; k < NK; ++k) {
        const __hip_bfloat16* xr = (k == 0) ? xb0 : (k == 1) ? xb1 : (k == 2) ? xb2 : xb3;
        const uint4* xp = (const uint4*)(xr + (long)v * 64 + b * 32);
        uint4 q0 = xp[0], q1 = xp[1], q2 = xp[2], q3 = xp[3];
        unsigned int qq[16] = {q0.x, q0.y, q0.z, q0.w, q1.x, q1.y, q1.z, q1.w,
                               q2.x, q2.y, q2.z, q2.w, q3.x, q3.y, q3.z, q3.w};
        const float* wk = weight + k * FOUT;
#pragma unroll
        for (int i = 0; i < 16; ++i) {
            float xlo = __uint_as_float(qq[i] << 16);
            float xhi = __uint_as_float(qq[i] & 0xffff0000u);
            const float* w0 = wk + (2 * i) * (NK * FOUT);
            const float* w1 = wk + (2 * i + 1) * (NK * FOUT);
#pragma unroll
            for (int o = 0; o < FOUT; ++o) {
                acc[o] = fmaf(xlo, w0[o], acc[o]);
                acc[o] = fmaf(xhi, w1[o], acc[o]);
            }
        }
    }
    float* op = out + (long)b * NV * FOUT + (long)v * FOUT;
#pragma unroll
    for (int o = 0; o < FOUT; ++o) op[o] = acc[o];
}

extern "C" void kernel_launch(void* const* d_in, const int* in_sizes, int n_in,
                              void* d_out, int out_size, void* d_ws, size_t ws_size,
                              hipStream_t stream) {
    const float* inputs = (const float*)d_in[0];
    const int*   rows   = (const int*)d_in[1];
    const int*   cols   = (const int*)d_in[2];
    const float* vals   = (const float*)d_in[3];
    const float* weight = (const float*)d_in[4];
    const float* bias   = (const float*)d_in[5];
    float* out = (float*)d_out;

    const long n = (long)NB * NV * FIN;            // 6.4M
    const int gG = (NB * NV) / 8;
    const int gChunk = (NE + CHUNK - 1) / CHUNK;   // 196
    const int gRow = (NV + 3) / 4;                 // 25000
    const int gConv = (int)(((long)NV * 64 + 255) / 256);
    const int gGemm = (NV * NB + 255) / 256;       // 782

    // ws layout
    int* bcount    = (int*)d_ws;                   // [1024]
    int* bstart    = bcount + 1024;                // [1024]
    int* gcursor   = bstart + 1024;                // [1024]
    int* row_start = gcursor + 1024;               // [NV]
    int* counts    = row_start + NV;               // [NV]
    ll* edges      = (ll*)(counts + NV);           // [NE], 8B-aligned (3*1024+2*NV ints)
    size_t off = (size_t)((char*)(edges + NE) - (char*)d_ws);
    off = (off + 255) & ~(size_t)255;
    __hip_bfloat16* xb0 = (__hip_bfloat16*)((char*)d_ws + off);
    __hip_bfloat16* xb1 = xb0 + (long)NV * 64;
    __hip_bfloat16* xb2 = xb1 + (long)NV * 64;
    __hip_bfloat16* xb3 = xb2 + (long)NV * 64;
    ll* edges_tmp = (ll*)xb3;                      // aliases xb3: tmp dead before gather-3 writes xb3
    size_t need = off + 4 * (size_t)NV * 64 * sizeof(__hip_bfloat16);

    if (ws_size < need) {
        // fallback: round-0 atomic scatter path
        float* fA = (float*)d_ws;
        float* fB = fA + n;
        const int gNf = (int)((n + 255) / 256);
        const int gEf = (NE * 32 + 255) / 256;
        term_gemm_kernel<<<gG, 256, 0, stream>>>(out, inputs, weight, bias, 0, 1);
        scale_init_kernel<<<gNf, 256, 0, stream>>>(fA, inputs, 0.f, (int)n);
        spmm_scatter_kernel<<<gEf, 256, 0, stream>>>(fA, inputs, rows, cols, vals, 1.f);
        term_gemm_kernel<<<gG, 256, 0, stream>>>(out, fA, weight, bias, 1, 0);
        scale_init_kernel<<<gNf, 256, 0, stream>>>(fB, inputs, -1.f, (int)n);
        spmm_scatter_kernel<<<gEf, 256, 0, stream>>>(fB, fA, rows, cols, vals, 2.f);
        term_gemm_kernel<<<gG, 256, 0, stream>>>(out, fB, weight, bias, 2, 0);
        scale_init_kernel<<<gNf, 256, 0, stream>>>(fA, fA, -1.f, (int)n);
        spmm_scatter_kernel<<<gEf, 256, 0, stream>>>(fA, fB, rows, cols, vals, 2.f);
        term_gemm_kernel<<<gG, 256, 0, stream>>>(out, fA, weight, bias, 3, 0);
        return;
    }

    // hierarchical CSR build
    hipMemsetAsync(bcount, 0, (size_t)NBUCK * sizeof(int), stream);
    bucket_hist_kernel<<<gChunk, 256, 0, stream>>>(rows, bcount);
    bucket_scan_kernel<<<1, 1024, 0, stream>>>(bcount, bstart, gcursor);
    bucket_place_kernel<<<gChunk, 256, 0, stream>>>(rows, cols, vals, gcursor, edges_tmp);
    bucket_sort_kernel<<<NBUCK, 256, 0, stream>>>(edges_tmp, edges, bstart, bcount,
                                                  row_start, counts);

    // x0 -> bf16 [V, 64]
    convert_x0_kernel<<<gConv, 256, 0, stream>>>(xb0, inputs);

    // recursion
    spmm_gather_kernel<<<gRow, 256, 0, stream>>>(xb1, xb0, nullptr, row_start, counts,
                                                 edges, 1.f, 0.f);
    spmm_gather_kernel<<<gRow, 256, 0, stream>>>(xb2, xb1, xb0, row_start, counts,
                                                 edges, 2.f, -1.f);
    spmm_gather_kernel<<<gRow, 256, 0, stream>>>(xb3, xb2, xb1, row_start, counts,
                                                 edges, 2.f, -1.f);

    // fused einsum over all 4 terms
    final_gemm_kernel<<<gGemm, 256, 0, stream>>>(out, xb0, xb1, xb2, xb3, weight, bias);
}